// Round 1
// baseline (729.844 us; speedup 1.0000x reference)
//
#include <hip/hip_runtime.h>
#include <hip/hip_bf16.h>

// Problem constants
#define B_   8
#define N_   128
#define HW_  16384
#define C_   768
#define NIN_ 1545
#define NINP_ 1600   // padded K for layer-1 GEMM (multiple of 64)
#define D1_  512
#define D_   256
#define EO_  128

typedef short s16x8 __attribute__((ext_vector_type(8)));
typedef float f32x16 __attribute__((ext_vector_type(16)));

__device__ __forceinline__ unsigned short f2bf(float x) {
  union { __hip_bfloat16 h; unsigned short u; } cv;
  cv.h = __float2bfloat16(x);
  return cv.u;
}

// ---------------- kernel 1: mask stats (sum, centroid -> motion) ------------
__global__ __launch_bounds__(256) void mask_stats_k(const float* __restrict__ masks,
                                                    const float* __restrict__ depth,
                                                    const float* __restrict__ pose,
                                                    float4* __restrict__ stats) {
  int row = blockIdx.x;            // b*128 + n
  int b = row >> 7;
  const float4* mp = (const float4*)(masks + (size_t)row * HW_);
  double s = 0.0, sx = 0.0, sy = 0.0;
  for (int it = 0; it < 16; ++it) {
    int i4 = threadIdx.x + it * 256;
    float4 v = mp[i4];
    int flat = i4 * 4;
    int y = flat >> 7, xb = flat & 127;
    double rs = (double)v.x + (double)v.y + (double)v.z + (double)v.w;
    s += rs;
    sx += (double)v.x * xb + (double)v.y * (xb + 1) + (double)v.z * (xb + 2) + (double)v.w * (xb + 3);
    sy += rs * (double)y;
  }
  for (int off = 32; off; off >>= 1) {
    s  += __shfl_down(s,  off);
    sx += __shfl_down(sx, off);
    sy += __shfl_down(sy, off);
  }
  __shared__ double red[3][4];
  int w = threadIdx.x >> 6, l = threadIdx.x & 63;
  if (l == 0) { red[0][w] = s; red[1][w] = sx; red[2][w] = sy; }
  __syncthreads();
  if (threadIdx.x == 0) {
    s  = red[0][0] + red[0][1] + red[0][2] + red[0][3];
    sx = red[1][0] + red[1][1] + red[1][2] + red[1][3];
    sy = red[2][0] + red[2][1] + red[2][2] + red[2][3];
    double msum = s + 1e-6;
    double cx = sx / msum, cy = sy / msum;
    int cxi = (int)rint(cx); cxi = min(127, max(0, cxi));
    int cyi = (int)rint(cy); cyi = min(127, max(0, cyi));
    double z = (double)depth[(size_t)b * HW_ + cyi * 128 + cxi];
    // K = I3: X = cx*z, Y = cy*z
    double Ph[4] = { cx * z, cy * z, z, 1.0 };
    const float* P = pose + b * 16;
    double pn[4];
    #pragma unroll
    for (int r = 0; r < 4; ++r)
      pn[r] = (double)P[r*4+0]*Ph[0] + (double)P[r*4+1]*Ph[1] + (double)P[r*4+2]*Ph[2] + (double)P[r*4+3]*Ph[3];
    double inv3 = 1.0 / pn[3];
    stats[row] = make_float4((float)(1.0 / msum), (float)(pn[0]*inv3), (float)(pn[1]*inv3), (float)(pn[2]*inv3));
  }
}

// ---------------- weight conversion to bf16 (with padding / re-layout) ------
__global__ __launch_bounds__(256) void convw_k(const float* __restrict__ w1,
                                               const float* __restrict__ w2,
                                               const float* __restrict__ ew1,
                                               const float* __restrict__ ew2,
                                               unsigned short* __restrict__ w1b,
                                               unsigned short* __restrict__ w2b,
                                               unsigned short* __restrict__ we1b,
                                               unsigned short* __restrict__ ew2b) {
  int i = blockIdx.x * 256 + threadIdx.x;
  if (i < 512 * NINP_) {                       // node_w1 -> 512 x 1600 (pad 0)
    int r = i / NINP_, k = i - r * NINP_;
    w1b[i] = f2bf(k < NIN_ ? w1[r * NIN_ + k] : 0.0f);
    return;
  }
  i -= 512 * NINP_;
  if (i < 256 * 512) { w2b[i] = f2bf(w2[i]); return; }   // node_w2 256x512
  i -= 256 * 512;
  if (i < 512 * 256) {                         // [w1a; w1b] rows: 512 x 256
    int r = i >> 8, k = i & 255;
    we1b[i] = f2bf(r < 256 ? ew1[r * 512 + k] : ew1[(r - 256) * 512 + 256 + k]);
    return;
  }
  i -= 512 * 256;
  if (i < 128 * 256) { ew2b[i] = f2bf(ew2[i]); }          // edge_w2 128x256
}

// ---------------- kernel 2: pooled = masks @ feats^T (split-K, bf16 MFMA) ---
// grid (48, 8): x = kc*6 + ct, y = b. Tile 128(mask rows) x 128(channels), BK=64.
__global__ __launch_bounds__(256) void pooled_k(const float* __restrict__ masks,
                                                const float* __restrict__ feats,
                                                float* __restrict__ Spart) {
  __shared__ short As[128 * 72];
  __shared__ short Bs[128 * 72];
  int bx = blockIdx.x;
  int ct = bx % 6, kc = bx / 6;
  int b = blockIdx.y;
  const float* mb = masks + (size_t)b * N_ * HW_;
  const float* fb = feats + ((size_t)b * C_ + (size_t)ct * 128) * HW_;
  int t = threadIdx.x, w = t >> 6, l = t & 63;
  int rsel = l & 31, khalf = l >> 5;
  f32x16 acc[4];
  #pragma unroll
  for (int nt = 0; nt < 4; ++nt)
    #pragma unroll
    for (int i = 0; i < 16; ++i) acc[nt][i] = 0.0f;

  for (int kt = 0; kt < 32; ++kt) {
    int kbase = kc * 2048 + kt * 64;
    #pragma unroll
    for (int c = 0; c < 8; ++c) {
      int chunk = t + 256 * c;           // 0..2047
      int row = chunk >> 4;              // 0..127
      int kof = (chunk & 15) << 2;       // 0..60
      float4 va = *(const float4*)(mb + (size_t)row * HW_ + kbase + kof);
      ushort4 pa = { f2bf(va.x), f2bf(va.y), f2bf(va.z), f2bf(va.w) };
      *(ushort4*)((unsigned short*)As + row * 72 + kof) = pa;
      float4 vb = *(const float4*)(fb + (size_t)row * HW_ + kbase + kof);
      ushort4 pb = { f2bf(vb.x), f2bf(vb.y), f2bf(vb.z), f2bf(vb.w) };
      *(ushort4*)((unsigned short*)Bs + row * 72 + kof) = pb;
    }
    __syncthreads();
    #pragma unroll
    for (int ks = 0; ks < 4; ++ks) {
      s16x8 a = *(const s16x8*)&As[(w * 32 + rsel) * 72 + ks * 16 + khalf * 8];
      #pragma unroll
      for (int nt = 0; nt < 4; ++nt) {
        s16x8 bf = *(const s16x8*)&Bs[(nt * 32 + rsel) * 72 + ks * 16 + khalf * 8];
        acc[nt] = __builtin_amdgcn_mfma_f32_32x32x16_bf16(a, bf, acc[nt], 0, 0, 0);
      }
    }
    __syncthreads();
  }
  float* op = Spart + (size_t)kc * (B_ * N_ * C_ / 8 * 8) / 8 * 8; // avoid miscompute; recompute below
  op = Spart + (size_t)kc * 786432 + (size_t)b * 98304;
  #pragma unroll
  for (int nt = 0; nt < 4; ++nt)
    #pragma unroll
    for (int reg = 0; reg < 16; ++reg) {
      int rm = w * 32 + (reg & 3) + 8 * (reg >> 2) + 4 * khalf;
      int cn = ct * 128 + nt * 32 + rsel;
      op[rm * C_ + cn] = acc[nt][reg];
    }
}

// ---------------- kernel 3a: reduce split-K partials + assemble node_input --
__global__ __launch_bounds__(256) void assemble_k(const float* __restrict__ Spart,
                                                  const float4* __restrict__ stats,
                                                  const float* __restrict__ obj,
                                                  const float* __restrict__ bboxes,
                                                  const float* __restrict__ conf,
                                                  unsigned short* __restrict__ ni) {
  int r = blockIdx.x;
  float4 st = stats[r];
  float x1 = bboxes[r*4+0], y1 = bboxes[r*4+1], x2 = bboxes[r*4+2], y2 = bboxes[r*4+3];
  for (int k = threadIdx.x; k < NINP_; k += 256) {
    float v;
    if (k < 768) {
      float acc = 0.0f;
      #pragma unroll
      for (int kc = 0; kc < 8; ++kc) acc += Spart[(size_t)kc * 786432 + (size_t)r * C_ + k];
      v = acc * st.x;
    } else if (k < 1537) v = obj[(size_t)r * 769 + (k - 768)];
    else if (k == 1537) v = 0.5f * (x1 + x2);
    else if (k == 1538) v = 0.5f * (y1 + y2);
    else if (k == 1539) v = x2 - x1;
    else if (k == 1540) v = y2 - y1;
    else if (k == 1541) v = conf[r];
    else if (k == 1542) v = st.y;
    else if (k == 1543) v = st.z;
    else if (k == 1544) v = st.w;
    else v = 0.0f;
    ni[(size_t)r * NINP_ + k] = f2bf(v);
  }
}

// ---------------- generic 64x64 bf16 GEMM: C[m,n] = act(bias + A·B^T) -------
// A: M x K bf16 (row-major, stride K), B: N x K bf16. K multiple of 64.
template <bool RELU, bool BIAS, int OUTM>  // OUTM: 0 f32, 1 bf16, 2 both
__global__ __launch_bounds__(256) void gemm64_k(const unsigned short* __restrict__ A,
                                                const unsigned short* __restrict__ Bm,
                                                const float* __restrict__ bias,
                                                float* __restrict__ Cf,
                                                unsigned short* __restrict__ Cb,
                                                int K, int N) {
  __shared__ short As[64 * 72];
  __shared__ short Bs[64 * 72];
  int n0 = blockIdx.x * 64, m0 = blockIdx.y * 64;
  int t = threadIdx.x, w = t >> 6, l = t & 63;
  int rsel = l & 31, khalf = l >> 5;
  int mh = (w & 1) * 32, nh = (w >> 1) * 32;
  f32x16 acc;
  #pragma unroll
  for (int i = 0; i < 16; ++i) acc[i] = 0.0f;

  for (int k0 = 0; k0 < K; k0 += 64) {
    #pragma unroll
    for (int c = 0; c < 2; ++c) {
      int chunk = t + 256 * c;            // 0..511
      int row = chunk >> 3, kof = (chunk & 7) * 8;
      *(uint4*)((unsigned short*)As + row * 72 + kof) =
          *(const uint4*)&A[(size_t)(m0 + row) * K + k0 + kof];
      *(uint4*)((unsigned short*)Bs + row * 72 + kof) =
          *(const uint4*)&Bm[(size_t)(n0 + row) * K + k0 + kof];
    }
    __syncthreads();
    #pragma unroll
    for (int ks = 0; ks < 4; ++ks) {
      s16x8 a = *(const s16x8*)&As[(mh + rsel) * 72 + ks * 16 + khalf * 8];
      s16x8 bf = *(const s16x8*)&Bs[(nh + rsel) * 72 + ks * 16 + khalf * 8];
      acc = __builtin_amdgcn_mfma_f32_32x32x16_bf16(a, bf, acc, 0, 0, 0);
    }
    __syncthreads();
  }
  #pragma unroll
  for (int reg = 0; reg < 16; ++reg) {
    int rm = m0 + mh + (reg & 3) + 8 * (reg >> 2) + 4 * khalf;
    int cn = n0 + nh + rsel;
    float v = acc[reg];
    if (BIAS) v += bias[cn];
    if (RELU) v = fmaxf(v, 0.0f);
    if (OUTM == 0 || OUTM == 2) Cf[(size_t)rm * N + cn] = v;
    if (OUTM == 1 || OUTM == 2) Cb[(size_t)rm * N + cn] = f2bf(v);
  }
}

// ---------------- kernel 4: edge MLP, fused he construction -----------------
// One workgroup per (b,i). he[j,k]=relu(hi[i,k]+hj[j,k]+b1[k]) built in-reg,
// GEMM vs w2 (128x256 bf16 in LDS), out edge_emb[b,i,j,o].
__global__ __launch_bounds__(256) void edge_k(const float* __restrict__ hihj,
                                              const unsigned short* __restrict__ ew2b,
                                              const float* __restrict__ eb1,
                                              const float* __restrict__ eb2,
                                              float* __restrict__ out_edge) {
  __shared__ short W2s[128 * 264];
  __shared__ float hi_s[256];
  __shared__ float b1_s[256];
  __shared__ float b2_s[128];
  int bi = blockIdx.x;             // b*128 + i
  int b = bi >> 7;
  int t = threadIdx.x, w = t >> 6, l = t & 63;
  int rsel = l & 31, khalf = l >> 5;

  #pragma unroll
  for (int c = 0; c < 16; ++c) {
    int chunk = t + 256 * c;       // 0..4095
    int row = chunk >> 5, kof = (chunk & 31) * 8;
    *(uint4*)((unsigned short*)W2s + row * 264 + kof) = *(const uint4*)&ew2b[row * 256 + kof];
  }
  hi_s[t] = hihj[(size_t)bi * 512 + t];      // t<256: hi of node i
  b1_s[t] = eb1[t];
  if (t < 128) b2_s[t] = eb2[t];
  __syncthreads();

  f32x16 acc[4];
  #pragma unroll
  for (int nt = 0; nt < 4; ++nt)
    #pragma unroll
    for (int i = 0; i < 16; ++i) acc[nt][i] = 0.0f;

  const float* hjb = hihj + (size_t)b * 128 * 512 + 256;
  int jrow = w * 32 + rsel;
  #pragma unroll
  for (int ks = 0; ks < 16; ++ks) {
    int k0 = ks * 16 + khalf * 8;
    const float* hp = hjb + (size_t)jrow * 512 + k0;
    float4 h0 = *(const float4*)hp;
    float4 h1 = *(const float4*)(hp + 4);
    float f[8] = { h0.x, h0.y, h0.z, h0.w, h1.x, h1.y, h1.z, h1.w };
    s16x8 a;
    #pragma unroll
    for (int c = 0; c < 8; ++c)
      a[c] = (short)f2bf(fmaxf(f[c] + hi_s[k0 + c] + b1_s[k0 + c], 0.0f));
    #pragma unroll
    for (int nt = 0; nt < 4; ++nt) {
      s16x8 bf = *(const s16x8*)&W2s[(nt * 32 + rsel) * 264 + k0];
      acc[nt] = __builtin_amdgcn_mfma_f32_32x32x16_bf16(a, bf, acc[nt], 0, 0, 0);
    }
  }
  float* ob = out_edge + (size_t)bi * 128 * 128;
  #pragma unroll
  for (int nt = 0; nt < 4; ++nt)
    #pragma unroll
    for (int reg = 0; reg < 16; ++reg) {
      int j = w * 32 + (reg & 3) + 8 * (reg >> 2) + 4 * khalf;
      int o = nt * 32 + rsel;
      ob[(size_t)j * 128 + o] = acc[nt][reg] + b2_s[o];
    }
}

// ---------------- kernel 5: adjacency ---------------------------------------
__global__ __launch_bounds__(128) void adj_k(const float* __restrict__ ne,
                                             float* __restrict__ adj) {
  int bi = blockIdx.x;   // b*128 + i
  int b = bi >> 7;
  __shared__ float nei[256];
  int t = threadIdx.x;
  nei[t] = ne[(size_t)bi * 256 + t];
  nei[t + 128] = ne[(size_t)bi * 256 + t + 128];
  __syncthreads();
  const float* nj = ne + ((size_t)b * 128 + t) * 256;
  float dot = 0.0f, sqj = 0.0f, sqi = 0.0f;
  for (int k = 0; k < 256; ++k) {
    float a = nei[k], c = nj[k];
    dot += a * c; sqj += c * c; sqi += a * a;
  }
  float d2 = fmaxf(sqi + sqj - 2.0f * dot, 0.0f);
  float d = d2 > 0.0f ? sqrtf(d2) : 0.0f;
  adj[(size_t)bi * 128 + t] = expf(-d);
}

// ---------------- launch -----------------------------------------------------
extern "C" void kernel_launch(void* const* d_in, const int* in_sizes, int n_in,
                              void* d_out, int out_size, void* d_ws, size_t ws_size,
                              hipStream_t stream) {
  const float* obj    = (const float*)d_in[0];
  const float* masks  = (const float*)d_in[1];
  const float* feats  = (const float*)d_in[2];
  const float* bboxes = (const float*)d_in[3];
  const float* conf   = (const float*)d_in[4];
  const float* depth  = (const float*)d_in[5];
  const float* pose   = (const float*)d_in[6];
  const float* nw1    = (const float*)d_in[7];
  const float* nb1    = (const float*)d_in[8];
  const float* nw2    = (const float*)d_in[9];
  const float* nb2    = (const float*)d_in[10];
  const float* ew1    = (const float*)d_in[11];
  const float* eb1    = (const float*)d_in[12];
  const float* ew2    = (const float*)d_in[13];
  const float* eb2    = (const float*)d_in[14];

  char* ws = (char*)d_ws;
  // Spart: 8 * 786432 f32 = 25165824 B. h_bf / ne_bf / hihj are carved out of
  // the Spart region (Spart is dead after assemble_k runs).
  float*          Spart = (float*)ws;
  unsigned short* h_bf  = (unsigned short*)ws;                    // 1024x512 bf16 = 1 MiB
  unsigned short* ne_bf = (unsigned short*)(ws + 1048576);        // 1024x256 bf16 = 512 KiB
  float*          hihj  = (float*)(ws + 1572864);                 // 1024x512 f32 = 2 MiB
  float4*         stats = (float4*)(ws + 25165824);               // 16 KiB
  unsigned short* ni_bf = (unsigned short*)(ws + 25182208);       // 1024x1600 bf16
  unsigned short* w1b   = (unsigned short*)(ws + 28459008);       // 512x1600 bf16
  unsigned short* w2b   = (unsigned short*)(ws + 30097408);       // 256x512 bf16
  unsigned short* we1b  = (unsigned short*)(ws + 30359552);       // 512x256 bf16
  unsigned short* ew2b  = (unsigned short*)(ws + 30621696);       // 128x256 bf16
  // total used: 30687232 B (~29.3 MiB)

  float* out      = (float*)d_out;
  float* out_ne   = out;                         // 8*128*256
  float* out_edge = out + 262144;                // 8*128*128*128
  float* out_adj  = out + 262144 + 16777216;     // 8*128*128

  mask_stats_k<<<dim3(1024), dim3(256), 0, stream>>>(masks, depth, pose, stats);
  convw_k<<<dim3(4352), dim3(256), 0, stream>>>(nw1, nw2, ew1, ew2, w1b, w2b, we1b, ew2b);
  pooled_k<<<dim3(48, 8), dim3(256), 0, stream>>>(masks, feats, Spart);
  assemble_k<<<dim3(1024), dim3(256), 0, stream>>>(Spart, stats, obj, bboxes, conf, ni_bf);
  gemm64_k<true,  true,  1><<<dim3(8, 16), dim3(256), 0, stream>>>(ni_bf, w1b, nb1, nullptr, h_bf, NINP_, 512);
  gemm64_k<false, true,  2><<<dim3(4, 16), dim3(256), 0, stream>>>(h_bf, w2b, nb2, out_ne, ne_bf, 512, 256);
  gemm64_k<false, false, 0><<<dim3(8, 16), dim3(256), 0, stream>>>(ne_bf, we1b, nullptr, hihj, nullptr, 256, 512);
  edge_k<<<dim3(1024), dim3(256), 0, stream>>>(hihj, ew2b, eb1, eb2, out_edge);
  adj_k<<<dim3(1024), dim3(128), 0, stream>>>(out_ne, out_adj);
}